// Round 1
// baseline (772.229 us; speedup 1.0000x reference)
//
#include <hip/hip_runtime.h>
#include <math.h>

#define NB 4
#define T 65536
#define TIN 8192
#define LL 256
#define KCL 6144   // per-layer kernel channels = 32*64*3

__device__ __forceinline__ float lrelu_f(float v) { return v >= 0.f ? v : 0.2f * v; }

// ---------------- prep1: one-time weight transposes (scalar-load friendly layouts) ----------------
// trb  [conv 6][c*3+k 192][oc 64]      from rb_w1/rb_w2 [i][oc][c][k]
// tbw  [J 192][o 256]                  from bias_w [o][J]
// tkpin[(cin*5+k) 500][oc 64]          from kp_in_w [oc][cin][k]
// tcvt [mtp 2][i 64][mm 128]           convt wm layout, contiguous per-wave 16
// tlvc [layer 4][c*3+k 96][oc 32]      from lvc_w [layer][oc][c][k]
__global__ void __launch_bounds__(256) prep1(
    const float* __restrict__ bias_w, const float* __restrict__ rb_w1,
    const float* __restrict__ rb_w2, const float* __restrict__ kp_in_w,
    const float* __restrict__ convt_w, const float* __restrict__ lvc_w,
    float* __restrict__ tbw, float* __restrict__ trb, float* __restrict__ tkpin,
    float* __restrict__ tcvt, float* __restrict__ tlvc) {
  __shared__ float t[64][193];
  const int bid = blockIdx.x, tid = threadIdx.x;
  if (bid < 10) {
    const float* src; float* dst; int dstride, dcol;
    if (bid < 6) {
      int i = bid >> 1, which = bid & 1;
      src = (which ? rb_w2 : rb_w1) + (size_t)i * 12288;
      dst = trb + (size_t)bid * 12288; dstride = 64; dcol = 0;
    } else {
      int ob = bid - 6;
      src = bias_w + (size_t)ob * 64 * 192;
      dst = tbw; dstride = 256; dcol = ob * 64;
    }
    for (int idx = tid; idx < 64 * 192; idx += 256) {
      int o = idx / 192, J = idx % 192;
      t[o][J] = src[(size_t)o * 192 + J];
    }
    __syncthreads();
    for (int idx = tid; idx < 64 * 192; idx += 256) {
      int J = idx >> 6, o = idx & 63;
      dst[(size_t)J * dstride + dcol + o] = t[o][J];
    }
  } else if (bid == 10) {
    for (int idx = tid; idx < 500 * 64; idx += 256) {
      int row = idx >> 6, o = idx & 63;
      tkpin[idx] = kp_in_w[o * 500 + row];
    }
  } else if (bid == 11) {
    for (int idx = tid; idx < 16384; idx += 256) {
      int mtp = idx >> 13, r = idx & 8191, i = r >> 7, mm = r & 127;
      int oo = mtp * 16 + (mm >> 3), k0 = mm & 7;
      tcvt[idx] = (i < 32) ? convt_w[i * 512 + oo * 16 + k0]
                           : convt_w[(i - 32) * 512 + oo * 16 + k0 + 8];
    }
  } else {
    for (int idx = tid; idx < 12288; idx += 256) {
      int layer = idx / 3072, r = idx % 3072, ck = r >> 5, o = r & 31;
      tlvc[idx] = lvc_w[(size_t)layer * 3072 + o * 96 + ck];
    }
  }
}

// per-layer kern_w transpose: tkwL[g 96][J 192][o 64]; channel(o) = layer*KCL + ci*192 + kk + 3*o
__global__ void __launch_bounds__(256) prep_kern(const float* __restrict__ kern_w,
                                                 float* __restrict__ tkwL, int layer) {
  __shared__ float t[64][193];
  const int g = blockIdx.x, tid = threadIdx.x;
  const int ci = g / 3, kk = g % 3;
  const float* src = kern_w + ((size_t)layer * KCL + ci * 192 + kk) * 192;
  float* dst = tkwL + (size_t)g * 12288;
  for (int idx = tid; idx < 64 * 192; idx += 256) {
    int o = idx / 192, J = idx % 192;
    t[o][J] = src[(size_t)o * 576 + J];
  }
  __syncthreads();
  for (int idx = tid; idx < 64 * 192; idx += 256) {
    int J = idx >> 6, o = idx & 63;
    dst[(size_t)J * 64 + o] = t[o][J];
  }
}

// ---------------- phase1: convt (264 blocks) + trunk (32 blocks) merged ----------------
// weights now come in via uniform scalar loads; LDS only holds x-data.
union Phase1LDS {
  struct { float xs[32][264]; } cvt;                       // 33.8 KB
  struct { float hs[64][56]; float xsp[20][56]; } trk;     // 18.8 KB
};

__global__ void __launch_bounds__(512) phase1(
    const float* __restrict__ x, const float* __restrict__ tcvt,
    const float* __restrict__ cbias, float* __restrict__ hout,
    const float* __restrict__ spec,
    const float* __restrict__ tkpin, const float* __restrict__ kp_in_b,
    const float* __restrict__ trb, const float* __restrict__ rb_b1,
    const float* __restrict__ rb_b2, float* __restrict__ kp_h) {
  __shared__ Phase1LDS u;
  const int bid = blockIdx.x;
  const int tid = threadIdx.x;
  const int lane = tid & 63;
  const int wvu = __builtin_amdgcn_readfirstlane(tid >> 6);  // uniform wave id -> s_loads

  if (bid < 264) {
    // ================= convt role =================
    const int bx = bid % 33;
    const int rr = bid / 33;
    const int mtp = rr & 1;
    const int b = rr >> 1;
    const int s0base = bx * 256;
    float (*xs)[264] = u.cvt.xs;

    const float* xb = x + (size_t)b * 32 * TIN;
    for (int idx = tid; idx < 32 * 64; idx += 512) {
      int c = idx >> 6, q = idx & 63;
      int p = s0base + q * 4;
      float4 v = (p + 3 < TIN) ? *(const float4*)(xb + c * TIN + p)
                               : make_float4(0.f, 0.f, 0.f, 0.f);
      *(float4*)&xs[c][4 + 4 * q] = v;
    }
    if (tid < 32) {
      int p = s0base - 1;
      xs[tid][3] = (p >= 0) ? xb[tid * TIN + p] : 0.f;
    }
    __syncthreads();

    float acc[2][8][4];   // [ol][k0][si]
#pragma unroll
    for (int ol = 0; ol < 2; ++ol) {
      float bo = cbias[mtp * 16 + wvu * 2 + ol];
#pragma unroll
      for (int k0 = 0; k0 < 8; ++k0)
#pragma unroll
        for (int si = 0; si < 4; ++si) acc[ol][k0][si] = bo;
    }

    const float* wcb = tcvt + (size_t)mtp * 8192 + wvu * 16;   // uniform base
    for (int c = 0; c < 32; ++c) {
      float w0[16], w1[16];
#pragma unroll
      for (int q = 0; q < 16; ++q) {
        w0[q] = wcb[c * 128 + q];          // s_load (uniform)
        w1[q] = wcb[(32 + c) * 128 + q];
      }
      float xm1[4], x0[4];
#pragma unroll
      for (int si = 0; si < 4; ++si) {
        xm1[si] = xs[c][lane + si * 64 + 3];
        x0[si]  = xs[c][lane + si * 64 + 4];
      }
#pragma unroll
      for (int ol = 0; ol < 2; ++ol)
#pragma unroll
        for (int k0 = 0; k0 < 8; ++k0)
#pragma unroll
          for (int si = 0; si < 4; ++si)
            acc[ol][k0][si] += x0[si] * w0[ol * 8 + k0] + xm1[si] * w1[ol * 8 + k0];
    }

#pragma unroll
    for (int ol = 0; ol < 2; ++ol) {
      float* ob = hout + ((size_t)b * 32 + mtp * 16 + wvu * 2 + ol) * T;
#pragma unroll
      for (int si = 0; si < 4; ++si) {
        int tb = (s0base + lane + si * 64) * 8 - 4;
        if (tb >= 0 && tb < T)
          *(float4*)(ob + tb) = make_float4(acc[ol][0][si], acc[ol][1][si],
                                            acc[ol][2][si], acc[ol][3][si]);
        if (tb + 4 >= 0 && tb + 4 < T)
          *(float4*)(ob + tb + 4) = make_float4(acc[ol][4][si], acc[ol][5][si],
                                                acc[ol][6][si], acc[ol][7][si]);
      }
    }
    return;
  }

  // ================= trunk role =================
  const int tb = bid - 264;
  const int lq = tb & 7, b = tb >> 3;
  const int j = lane;
  const int oc0 = wvu * 8;
  const int l0 = lq * 32;
  const int labs = l0 - 9 + j;
  const bool lvalid = (labs >= 0 && labs < 256);

  float (*hs)[56] = u.trk.hs;
  float (*xsp)[56] = u.trk.xsp;

  float px[3];
  auto pf_xsp = [&](int cc) {
#pragma unroll
    for (int t = 0; t < 3; ++t) {
      int idx = t * 512 + tid;
      px[t] = 0.f;
      if (idx < 1120) {
        int c = idx / 56, jj = idx - c * 56;
        int l = l0 - 9 + jj;
        if (l >= 0 && l < 256)
          px[t] = spec[((size_t)b * 100 + cc * 20 + c) * LL + l];
      }
    }
  };
  auto wr_xsp = [&]() {
#pragma unroll
    for (int t = 0; t < 3; ++t) {
      int idx = t * 512 + tid;
      if (idx < 1120) xsp[idx / 56][idx % 56] = px[t];
    }
  };
  auto conv64 = [&](int jlo, int jhi, const float* bptr, const float* wconv, float* a) {
#pragma unroll
    for (int oi = 0; oi < 8; ++oi) a[oi] = bptr[oc0 + oi];   // uniform s_load
    if (j >= jlo && j < jhi) {
      for (int c = 0; c < 64; ++c) {
        const float* wp = wconv + (size_t)(c * 3) * 64 + oc0;  // uniform
        float w0[8], w1[8], w2[8];
#pragma unroll
        for (int oi = 0; oi < 8; ++oi) {
          w0[oi] = wp[oi];
          w1[oi] = wp[64 + oi];
          w2[oi] = wp[128 + oi];
        }
        float x0 = hs[c][j - 1], x1 = hs[c][j], x2 = hs[c][j + 1];
#pragma unroll
        for (int oi = 0; oi < 8; ++oi)
          a[oi] += x0 * w0[oi] + x1 * w1[oi] + x2 * w2[oi];
      }
    }
  };

  // ---- kp_in: 5 cc pages (only spec staged; weights via s_load) ----
  pf_xsp(0);
  wr_xsp();
  __syncthreads();

  float acc[8];
#pragma unroll
  for (int oi = 0; oi < 8; ++oi) acc[oi] = kp_in_b[oc0 + oi];

  for (int cc = 0; cc < 5; ++cc) {
    if (cc < 4) pf_xsp(cc + 1);
    if (j >= 2 && j < 48) {
      for (int c = 0; c < 20; ++c) {
        float x5[5];
#pragma unroll
        for (int u2 = 0; u2 < 5; ++u2) x5[u2] = xsp[c][j - 2 + u2];
        const float* wp = tkpin + (size_t)((cc * 20 + c) * 5) * 64 + oc0;  // uniform
#pragma unroll
        for (int k = 0; k < 5; ++k) {
          float w8[8];
#pragma unroll
          for (int oi = 0; oi < 8; ++oi) w8[oi] = wp[k * 64 + oi];
#pragma unroll
          for (int oi = 0; oi < 8; ++oi) acc[oi] += x5[k] * w8[oi];
        }
      }
    }
    if (cc == 4 && j >= 2 && j < 48) {
#pragma unroll
      for (int oi = 0; oi < 8; ++oi) hs[oc0 + oi][j] = lvalid ? acc[oi] : 0.f;
    }
    __syncthreads();
    if (cc < 4) wr_xsp();
    __syncthreads();
  }

  // ---- 3 residual blocks ----
  for (int i = 0; i < 3; ++i) {
    const int jlo1 = 3 + 2 * i, jhi1 = 47 - 2 * i;
    const int jlo2 = jlo1 + 1, jhi2 = jhi1 - 1;
    float r[8];
    if (j >= jlo2 && j < jhi2) {
#pragma unroll
      for (int oi = 0; oi < 8; ++oi) r[oi] = hs[oc0 + oi][j];
    }
    float a1[8];
    conv64(jlo1, jhi1, rb_b1 + i * 64, trb + (size_t)(2 * i) * 12288, a1);
    __syncthreads();
    if (j >= jlo1 && j < jhi1) {
#pragma unroll
      for (int oi = 0; oi < 8; ++oi) hs[oc0 + oi][j] = lvalid ? lrelu_f(a1[oi]) : 0.f;
    }
    __syncthreads();
    float a2[8];
    conv64(jlo2, jhi2, rb_b2 + i * 64, trb + (size_t)(2 * i + 1) * 12288, a2);
    __syncthreads();
    if (j >= jlo2 && j < jhi2) {
#pragma unroll
      for (int oi = 0; oi < 8; ++oi) hs[oc0 + oi][j] = lvalid ? (lrelu_f(a2[oi]) + r[oi]) : 0.f;
    }
    __syncthreads();
  }

  // ---- write kp_h (central 32 cols) ----
  for (int idx = tid; idx < 64 * 32; idx += 512) {
    int c = idx >> 5, jj = idx & 31;
    kp_h[((size_t)b * 64 + c) * LL + l0 + jj] = hs[c][9 + jj];
  }
}

// ---------------- kern head GEMM (+ bias head blocks at bx>=192 on layer 0) ----------------
// weights via uniform s_load from tkwL/tbw; x via ds_read_b128 (col = 4*lane+q)
__global__ void __launch_bounds__(256, 4) kern_head(const float* __restrict__ kp_h,
                                                    const float* __restrict__ tkwL,
                                                    const float* __restrict__ kb,
                                                    const float* __restrict__ tbw,
                                                    const float* __restrict__ bias_b,
                                                    float* __restrict__ kh,
                                                    float* __restrict__ bh, int layer) {
  const int bx = blockIdx.x, b = blockIdx.y;
  const bool isbias = (bx >= 192);
  const int tid = threadIdx.x, lane = tid & 63;
  const int wvu = __builtin_amdgcn_readfirstlane(tid >> 6);
  __shared__ float xs[32][264];

  int g = 0, oc0 = 0, ci = 0, kk = 0, ocb0 = 0;
  const float* wbase;
  int wstride;
  if (!isbias) {
    g = bx >> 1; oc0 = (bx & 1) * 32;
    ci = g / 3; kk = g - ci * 3;
    wbase = tkwL + (size_t)g * 12288 + oc0 + wvu * 8;
    wstride = 64;
  } else {
    ocb0 = (bx - 192) * 32;
    wbase = tbw + ocb0 + wvu * 8;
    wstride = 256;
  }

  float acc[8][4];   // [oi][q], col = 4*lane+q
#pragma unroll
  for (int oi = 0; oi < 8; ++oi) {
    float bv = isbias ? bias_b[ocb0 + wvu * 8 + oi]
                      : kb[layer * KCL + (ci * 64 + oc0 + wvu * 8 + oi) * 3 + kk];
#pragma unroll
    for (int q = 0; q < 4; ++q) acc[oi][q] = bv;
  }

  for (int half = 0; half < 2; ++half) {
    const int hc0 = half * 32;
    __syncthreads();
    for (int idx = tid; idx < 32 * 64; idx += 256) {
      int c = idx >> 6, q = idx & 63;
      *(float4*)&xs[c][4 + 4 * q] =
          *(const float4*)(kp_h + ((size_t)b * 64 + hc0 + c) * LL + 4 * q);
    }
    if (tid < 32) { xs[tid][3] = 0.f; xs[tid][260] = 0.f; }
    __syncthreads();
    const float* wb2 = wbase + (size_t)(hc0 * 3) * wstride;
    for (int c = 0; c < 32; ++c) {
      float w[3][8];
#pragma unroll
      for (int t3 = 0; t3 < 3; ++t3)
#pragma unroll
        for (int oi = 0; oi < 8; ++oi)
          w[t3][oi] = wb2[(size_t)(c * 3 + t3) * wstride + oi];   // uniform s_load
      float4 xa = *(const float4*)&xs[c][4 * lane];        // only .w used
      float4 xm = *(const float4*)&xs[c][4 + 4 * lane];
      float4 xb = *(const float4*)&xs[c][8 + 4 * lane];    // only .x used
      float xx[6] = {xa.w, xm.x, xm.y, xm.z, xm.w, xb.x};
#pragma unroll
      for (int t3 = 0; t3 < 3; ++t3)
#pragma unroll
        for (int oi = 0; oi < 8; ++oi)
#pragma unroll
          for (int q = 0; q < 4; ++q)
            acc[oi][q] += w[t3][oi] * xx[q + t3];
    }
  }

  if (!isbias) {
#pragma unroll
    for (int q = 0; q < 4; ++q) {
      int l = 4 * lane + q;
      float* op = kh + ((size_t)b * LL + l) * KCL + g * 64 + oc0 + wvu * 8;
      *(float4*)(op)     = make_float4(acc[0][q], acc[1][q], acc[2][q], acc[3][q]);
      *(float4*)(op + 4) = make_float4(acc[4][q], acc[5][q], acc[6][q], acc[7][q]);
    }
  } else {
#pragma unroll
    for (int oi = 0; oi < 8; ++oi) {
      float* op = bh + ((size_t)b * 256 + ocb0 + wvu * 8 + oi) * LL + 4 * lane;
      *(float4*)op = make_float4(acc[oi][0], acc[oi][1], acc[oi][2], acc[oi][3]);
    }
  }
}

// ---------------- fused dilated conv + LVC + gate + residual ----------------
// LVC kernels & conv weights via uniform s_load; LDS holds only xh -> 4 blocks/CU
__global__ void __launch_bounds__(512, 8) layer_fused(
    const float* __restrict__ kh, const float* __restrict__ bh,
    const float* __restrict__ wT, const float* __restrict__ bias,
    const float* __restrict__ hin, float* __restrict__ hout,
    int layer, int dil) {
  const int l = blockIdx.x, b = blockIdx.y;
  const int tid = threadIdx.x, lane = tid & 63;
  const int wvu = __builtin_amdgcn_readfirstlane(tid >> 6);
  const int t0 = l * 256;
  __shared__ float xh[32][316];   // 40.4 KB

  const float* hb = hin + (size_t)b * 32 * T;
  for (int idx = tid; idx < 32 * 64; idx += 512) {
    int c = idx >> 6, q = idx & 63;
    float4 v = *(const float4*)(hb + (size_t)c * T + t0 + 4 * q);
    *(float4*)&xh[c][32 + 4 * q] = make_float4(lrelu_f(v.x), lrelu_f(v.y),
                                               lrelu_f(v.z), lrelu_f(v.w));
  }
  for (int idx = tid; idx < 32 * 60; idx += 512) {
    int c = idx / 60, r = idx - c * 60;
    int jj = (r < 32) ? r : (256 + r);
    int t = t0 + jj - 32;
    xh[c][jj] = (t >= 0 && t < T) ? lrelu_f(hb[(size_t)c * T + t]) : 0.f;
  }
  __syncthreads();

  // Phase B: dilated conv -> y regs. wave owns oc4 = wvu*4; col = lane + si*64, col<258.
  const int oc4 = wvu * 4;
  float yv[5][4];
  {
    float a[5][4];
#pragma unroll
    for (int oi = 0; oi < 4; ++oi) {
      float bv = bias[oc4 + oi];
#pragma unroll
      for (int si = 0; si < 5; ++si) a[si][oi] = bv;
    }
    for (int c = 0; c < 32; ++c) {
#pragma unroll
      for (int k = 0; k < 3; ++k) {
        const float* wp = wT + (size_t)(c * 3 + k) * 32 + oc4;   // uniform s_load
        float wq0 = wp[0], wq1 = wp[1], wq2 = wp[2], wq3 = wp[3];
        float xv[5];
#pragma unroll
        for (int si = 0; si < 5; ++si) {
          int col = lane + si * 64;
          int colc = (col < 258) ? col : 257;
          xv[si] = xh[c][colc + 31 + (k - 1) * dil];
        }
#pragma unroll
        for (int si = 0; si < 5; ++si) {
          a[si][0] += xv[si] * wq0;
          a[si][1] += xv[si] * wq1;
          a[si][2] += xv[si] * wq2;
          a[si][3] += xv[si] * wq3;
        }
      }
    }
#pragma unroll
    for (int si = 0; si < 5; ++si) {
      int t = t0 - 1 + lane + si * 64;
      bool tval = (t >= 0 && t < T);
#pragma unroll
      for (int oi = 0; oi < 4; ++oi)
        yv[si][oi] = tval ? lrelu_f(a[si][oi]) : 0.f;
    }
  }
  __syncthreads();

  // Phase C: write y into xh central region
#pragma unroll
  for (int si = 0; si < 5; ++si) {
    int col = lane + si * 64;
    if (col < 258) {
#pragma unroll
      for (int oi = 0; oi < 4; ++oi) xh[oc4 + oi][col + 31] = yv[si][oi];
    }
  }
  __syncthreads();

  // Phase D: LVC (kernels direct from kh via scalar loads)
  const int oc8 = (wvu & 3) * 8;
  const int sh  = wvu >> 2;
  const float* krbase = kh + ((size_t)b * LL + l) * KCL;
  float acc_a[8][2], acc_g[8][2];
#pragma unroll
  for (int oi = 0; oi < 8; ++oi) {
    float ba = bh[((size_t)b * 256 + layer * 64 + oc8 + oi) * LL + l];
    float bg = bh[((size_t)b * 256 + layer * 64 + 32 + oc8 + oi) * LL + l];
#pragma unroll
    for (int si = 0; si < 2; ++si) { acc_a[oi][si] = ba; acc_g[oi][si] = bg; }
  }

  for (int c = 0; c < 32; ++c) {
#pragma unroll
    for (int k = 0; k < 3; ++k) {
      const float* kr = krbase + (size_t)(c * 3 + k) * 64;   // uniform
      float wa[8], wg[8];
#pragma unroll
      for (int oi = 0; oi < 8; ++oi) {
        wa[oi] = kr[oc8 + oi];
        wg[oi] = kr[32 + oc8 + oi];
      }
      float xv2[2];
#pragma unroll
      for (int si = 0; si < 2; ++si) {
        int s = lane + (sh * 2 + si) * 64;
        xv2[si] = xh[c][s + k + 31];
      }
#pragma unroll
      for (int oi = 0; oi < 8; ++oi)
#pragma unroll
        for (int si = 0; si < 2; ++si) {
          acc_a[oi][si] += wa[oi] * xv2[si];
          acc_g[oi][si] += wg[oi] * xv2[si];
        }
    }
  }

  // Phase E: gate + residual
#pragma unroll
  for (int oi = 0; oi < 8; ++oi) {
    const float* hip = hin + ((size_t)b * 32 + oc8 + oi) * T + t0;
    float* hop = hout + ((size_t)b * 32 + oc8 + oi) * T + t0;
#pragma unroll
    for (int si = 0; si < 2; ++si) {
      int s = lane + (sh * 2 + si) * 64;
      float a = acc_a[oi][si], g = acc_g[oi][si];
      float sg = 1.f / (1.f + __expf(-a));
      float th = tanhf(g);
      hop[s] = sg * th + hip[s];
    }
  }
}

extern "C" void kernel_launch(void* const* d_in, const int* in_sizes, int n_in,
                              void* d_out, int out_size, void* d_ws, size_t ws_size,
                              hipStream_t stream) {
  const float* hidden  = (const float*)d_in[0];
  const float* spec    = (const float*)d_in[1];
  const float* convt_w = (const float*)d_in[2];
  const float* convt_b = (const float*)d_in[3];
  const float* kp_in_w = (const float*)d_in[4];
  const float* kp_in_b = (const float*)d_in[5];
  const float* rb_w1   = (const float*)d_in[6];
  const float* rb_b1   = (const float*)d_in[7];
  const float* rb_w2   = (const float*)d_in[8];
  const float* rb_b2   = (const float*)d_in[9];
  const float* kern_w  = (const float*)d_in[10];
  const float* kern_b  = (const float*)d_in[11];
  const float* bias_w  = (const float*)d_in[12];
  const float* bias_b  = (const float*)d_in[13];
  const float* lvc_w   = (const float*)d_in[14];
  const float* lvc_b   = (const float*)d_in[15];

  float* wsp = (float*)d_ws;
  float* h_ws     = wsp;                                 // NB*32*T        = 8,388,608
  float* kh_layer = h_ws + (size_t)NB * 32 * T;          // NB*LL*KCL      = 6,291,456
  float* bh       = kh_layer + (size_t)NB * LL * KCL;    // NB*256*LL      =   262,144
  float* kp_h     = bh + (size_t)NB * 256 * LL;          // NB*64*LL       =    65,536
  float* tkwL     = kp_h + (size_t)NB * 64 * LL;         // 96*192*64      = 1,179,648
  float* tbw      = tkwL + (size_t)96 * 192 * 64;        // 192*256        =    49,152
  float* trb      = tbw + (size_t)192 * 256;             // 6*192*64       =    73,728
  float* tkpin    = trb + (size_t)6 * 192 * 64;          // 500*64         =    32,000
  float* tcvt     = tkpin + (size_t)500 * 64;            // 2*64*128       =    16,384
  float* tlvc     = tcvt + (size_t)2 * 64 * 128;         // 4*96*32        =    12,288
  // total ~16.37M floats = 65.5 MB

  float* h0 = (float*)d_out;
  float* h1 = h_ws;

  // 0) one-time weight transposes
  prep1<<<dim3(13), 256, 0, stream>>>(bias_w, rb_w1, rb_w2, kp_in_w, convt_w, lvc_w,
                                      tbw, trb, tkpin, tcvt, tlvc);

  // 1) merged convt + trunk
  phase1<<<dim3(296), 512, 0, stream>>>(hidden, tcvt, convt_b, h0,
                                        spec, tkpin, kp_in_b,
                                        trb, rb_b1, rb_b2, kp_h);

  static const int dil[4] = {1, 3, 9, 27};
  float* hin = h0;
  float* hout = h1;
  for (int layer = 0; layer < 4; ++layer) {
    prep_kern<<<dim3(96), 256, 0, stream>>>(kern_w, tkwL, layer);
    kern_head<<<dim3(layer == 0 ? 200 : 192, NB), 256, 0, stream>>>(
        kp_h, tkwL, kern_b, tbw, bias_b, kh_layer, bh, layer);
    layer_fused<<<dim3(LL, NB), 512, 0, stream>>>(
        kh_layer, bh, tlvc + (size_t)layer * 3072, lvc_b + layer * 32,
        hin, hout, layer, dil[layer]);
    float* tmp = hin; hin = hout; hout = tmp;
  }
  // after 4 swaps the final output landed in h0 = d_out
}